// Round 16
// baseline (347.499 us; speedup 1.0000x reference)
//
#include <hip/hip_runtime.h>
#include <hip/hip_bf16.h>

// Problem constants (AdaptiveMobiusLayer): B=4, S=4096, DIM=1024
#define PB 4
#define PS 4096
#define PD 1024
#define ROWS (PB * PS)          // 16384
#define NUM_CYCLES 3
#define BASE_COUPLING 0.1f
#define WSCALE 256.0f           // weight scale for fp8 (w std 1/32 -> 8)
#define INV_WSCALE (1.0f / 256.0f)

typedef __attribute__((ext_vector_type(8))) short bf16x8;
typedef __attribute__((ext_vector_type(4))) float f32x4;
typedef __attribute__((ext_vector_type(16))) float f32x16;

// ---------------- helpers ----------------
__device__ __forceinline__ float geluf(float x) {
    return 0.5f * x * (1.0f + erff(x * 0.70710678118654752440f));
}
__device__ __forceinline__ float gelu_fast(float x) {
    float u = (x + 0.044715f * x * x * x) * 2.3022077f;  // 2*0.7978845608*log2(e)
    return x * __builtin_amdgcn_rcpf(1.0f + exp2f(-u));
}
__device__ __forceinline__ float sigmf_(float x) {
    return 1.0f / (1.0f + expf(-x));
}
__device__ __forceinline__ uint2 pk4(float4 v) {
    __hip_bfloat16 h[4] = {__float2bfloat16(v.x), __float2bfloat16(v.y),
                           __float2bfloat16(v.z), __float2bfloat16(v.w)};
    return *reinterpret_cast<uint2*>(h);
}
__device__ __forceinline__ float4 axpy4(float4 a, float s, float4 b) {
    return make_float4(fmaf(s, b.x, a.x), fmaf(s, b.y, a.y),
                       fmaf(s, b.z, a.z), fmaf(s, b.w, a.w));
}
__device__ __forceinline__ float bf2f(unsigned short u) {
    unsigned int w = ((unsigned int)u) << 16;
    return __builtin_bit_cast(float, w);
}
__device__ __forceinline__ float4 ubf2f4(uint2 u) {
    unsigned short h[4];
    *reinterpret_cast<uint2*>(h) = u;
    return make_float4(bf2f(h[0]), bf2f(h[1]), bf2f(h[2]), bf2f(h[3]));
}
// manual e4m3fn encode: RNE, FTZ below 2^-6, saturate to 448 (0x7E)
__device__ __forceinline__ unsigned char f2e4m3(float x) {
    unsigned int u = __builtin_bit_cast(unsigned int, x);
    unsigned int s = (u >> 24) & 0x80u;
    float ax = __builtin_fabsf(x);
    if (!(ax >= 0.015625f)) return (unsigned char)s;      // FTZ + NaN->0
    if (ax >= 464.0f) return (unsigned char)(s | 0x7Eu);  // saturate
    unsigned int au = u & 0x7FFFFFFFu;
    unsigned int lsb = (au >> 20) & 1u;
    au += 0x0007FFFFu + lsb;                              // RNE to 3 mantissa bits
    unsigned int e = (au >> 23) - 127u + 7u;
    unsigned int m = (au >> 20) & 7u;
    if (e >= 16u) return (unsigned char)(s | 0x7Eu);
    return (unsigned char)(s | (e << 3) | m);
}
__device__ __forceinline__ unsigned int pk8(float4 v) {
    return (unsigned int)f2e4m3(v.x) | ((unsigned int)f2e4m3(v.y) << 8) |
           ((unsigned int)f2e4m3(v.z) << 16) | ((unsigned int)f2e4m3(v.w) << 24);
}

#define GLD_LDS16(gsrc, ldst)                                                        \
    __builtin_amdgcn_global_load_lds(                                                \
        (const __attribute__((address_space(1))) void*)(gsrc),                       \
        (__attribute__((address_space(3))) void*)(ldst), 16, 0, 0)

// ---------------- fused: outb8 = fp8(x) + partial mean over S ----------------
__global__ __launch_bounds__(256) void copy_mean_cvt_kernel(const float* __restrict__ x,
                                                            unsigned char* __restrict__ outb8,
                                                            float* __restrict__ part) {
    int b = blockIdx.x >> 7, sc = blockIdx.x & 127;
    size_t base = ((size_t)b * PS + (size_t)sc * 32) * PD;
    const float4* x4 = reinterpret_cast<const float4*>(x + base);
    unsigned int* o8 = reinterpret_cast<unsigned int*>(outb8 + base);
    int t = threadIdx.x;
    float4 acc = make_float4(0.f, 0.f, 0.f, 0.f);
    for (int r = 0; r < 32; ++r) {
        float4 v = x4[r * 256 + t];
        o8[r * 256 + t] = pk8(v);
        acc.x += v.x; acc.y += v.y; acc.z += v.z; acc.w += v.w;
    }
    reinterpret_cast<float4*>(part + ((size_t)(b * 128 + sc)) * PD)[t] = acc;
}

__global__ __launch_bounds__(256) void mean_stage2(const float* __restrict__ part,
                                                   float* __restrict__ gc) {
    int b = blockIdx.x, t = threadIdx.x;
    float4 s = make_float4(0.f, 0.f, 0.f, 0.f);
    for (int c = 0; c < 128; ++c) {
        float4 v = reinterpret_cast<const float4*>(part + ((size_t)(b * 128 + c)) * PD)[t];
        s.x += v.x; s.y += v.y; s.z += v.z; s.w += v.w;
    }
    s.x *= (1.0f / 4096.0f); s.y *= (1.0f / 4096.0f);
    s.z *= (1.0f / 4096.0f); s.w *= (1.0f / 4096.0f);
    reinterpret_cast<float4*>(gc + (size_t)b * PD)[t] = s;
}

// ---------------- weight transpose: W[K][N] f32 -> Wt8[N][K] fp8, scaled x256 ----------------
__global__ __launch_bounds__(256) void transpose_w8_kernel(const float* __restrict__ W,
                                                           unsigned char* __restrict__ Wt8,
                                                           int K, int N) {
    __shared__ float t[32][33];
    int k0 = blockIdx.x * 32, n0 = blockIdx.y * 32;
    int tx = threadIdx.x & 31, ty = threadIdx.x >> 5;
#pragma unroll
    for (int i = 0; i < 32; i += 8)
        t[ty + i][tx] = W[(size_t)(k0 + ty + i) * N + n0 + tx];
    __syncthreads();
#pragma unroll
    for (int i = 0; i < 32; i += 8)
        Wt8[(size_t)(n0 + ty + i) * K + k0 + tx] = f2e4m3(t[tx][ty + i] * WSCALE);
}

// ---------------- global context net, parallelized (f32, unchanged) ----------------
__global__ __launch_bounds__(256) void gn1_kernel(const float* __restrict__ gc,
                                                  const float* __restrict__ w1,
                                                  const float* __restrict__ b1,
                                                  float* __restrict__ g1) {
    __shared__ float gcs[1024];
    __shared__ float red[4][64];
    int b = blockIdx.x, j0 = blockIdx.y * 64;
    int t = threadIdx.x, wave = t >> 6, lane = t & 63;
    for (int i = t; i < 1024; i += 256) gcs[i] = gc[(size_t)b * PD + i];
    __syncthreads();
    int j = j0 + lane;
    float a = 0.f;
    int k0 = wave * 256;
    for (int k = k0; k < k0 + 256; ++k) a += gcs[k] * w1[(size_t)k * 512 + j];
    red[wave][lane] = a;
    __syncthreads();
    if (wave == 0) {
        float v = red[0][lane] + red[1][lane] + red[2][lane] + red[3][lane] + b1[j];
        g1[(size_t)b * 512 + j] = geluf(v);
    }
}

__global__ __launch_bounds__(256) void gn2_kernel(const float* __restrict__ g1,
                                                  const float* __restrict__ w2,
                                                  const float* __restrict__ b2,
                                                  float* __restrict__ g2) {
    __shared__ float g1s[512];
    __shared__ float red[4][64];
    int b = blockIdx.x, j0 = blockIdx.y * 64;
    int t = threadIdx.x, wave = t >> 6, lane = t & 63;
    for (int i = t; i < 512; i += 256) g1s[i] = g1[(size_t)b * 512 + i];
    __syncthreads();
    int j = j0 + lane;
    float a = 0.f;
    int k0 = wave * 128;
    for (int k = k0; k < k0 + 128; ++k) a += g1s[k] * w2[(size_t)k * 256 + j];
    red[wave][lane] = a;
    __syncthreads();
    if (wave == 0) {
        float v = red[0][lane] + red[1][lane] + red[2][lane] + red[3][lane] + b2[j];
        g2[(size_t)b * 256 + j] = geluf(v);
    }
}

__global__ __launch_bounds__(256) void gn3_kernel(const float* __restrict__ g2,
                                                  const float* __restrict__ w3,
                                                  const float* __restrict__ b3,
                                                  float* __restrict__ gf) {
    __shared__ float red[256];
    int b = blockIdx.x, t = threadIdx.x;
    red[t] = g2[(size_t)b * 256 + t] * w3[t];
    __syncthreads();
    for (int s = 128; s > 0; s >>= 1) {
        if (t < s) red[t] += red[t + s];
        __syncthreads();
    }
    if (t == 0) gf[b] = sigmf_(red[0] + b3[0]);
}

// ============ 128x128 BK=64 FP8 GEMM with 32x32x16 MFMA (layer 1) ============
// Same staging/swizzle/LDS as the 16x16 fp8 core (R15, verified); only the fragment
// geometry changes: wave tile 64x64 = 2x2 of 32x32; acc[2][2] f32x16.
// A/B frag (32x32x16 fp8, 2 VGPR = 8 fp8): row = lane&31, k = (lane>>5)*8 + i.
// C/D (m74/m101, dtype-indep): col = lane&31, row = (reg&3) + 8*(reg>>2) + 4*(lane>>5).
// 16 MFMA x ~8cyc per wave-K-tile vs 32 x ~4.85 -> fewer issue slots, better per-instr
// latency hiding. Reads: 16 x ds_read_b64 per K-tile (same bytes as 16x16 path).
template <int OUTFP8>
__global__ __launch_bounds__(256, 2) void gemm128f8x32_kernel(
    const unsigned char* __restrict__ A,
    const unsigned char* __restrict__ Wt,
    const float* __restrict__ bias,
    unsigned char* __restrict__ C8,
    __hip_bfloat16* __restrict__ Cb,
    int K, int N) {
    __shared__ __align__(16) unsigned char Als[2][128 * 64];
    __shared__ __align__(16) unsigned char Bls[2][128 * 64];
    const int tid = threadIdx.x;
    const int wave = tid >> 6, lane = tid & 63;
    const int m0 = blockIdx.x * 128, n0 = blockIdx.y * 128;
    const int wr = wave >> 1, wc = wave & 1;
    const int l31 = lane & 31, fq2 = lane >> 5;

    // staging identical to R15 fp8 core
    int sr[2], skel[2], sbase[2];
#pragma unroll
    for (int j = 0; j < 2; ++j) {
        int c = j * 256 + tid;
        int row = c >> 2;
        int inner = (c & 3) * 16;
        skel[j] = inner ^ ((row & 6) << 3);
        sr[j] = row;
        sbase[j] = (j * 256 + wave * 64) * 16;
    }
    // read offsets: [rowblock rb][kslice ks]
    int aoff[2][4], boff[2][4];
#pragma unroll
    for (int rb = 0; rb < 2; ++rb)
#pragma unroll
        for (int ks = 0; ks < 4; ++ks) {
            int rowA = wr * 64 + rb * 32 + l31;
            aoff[rb][ks] = rowA * 64 + ((ks * 16) ^ ((rowA & 6) << 3)) + fq2 * 8;
            int rowB = wc * 64 + rb * 32 + l31;
            boff[rb][ks] = rowB * 64 + ((ks * 16) ^ ((rowB & 6) << 3)) + fq2 * 8;
        }

    f32x16 acc[2][2] = {};
    long av[4], bv[2][4];

#define STAGE8(bufn, kt) do {                                                         \
    _Pragma("unroll") for (int j = 0; j < 2; ++j) {                                   \
        GLD_LDS16(A + (size_t)(m0 + sr[j]) * K + (kt) + skel[j], (char*)Als[bufn] + sbase[j]); \
        GLD_LDS16(Wt + (size_t)(n0 + sr[j]) * K + (kt) + skel[j], (char*)Bls[bufn] + sbase[j]); \
    }                                                                                 \
} while (0)

    STAGE8(0, 0);
    __syncthreads();

    const int nt = K >> 6;
    for (int t = 0; t < nt; ++t) {
        const int buf = t & 1;
        // B full (2 rb x 4 ks) + A rowblock 0
#pragma unroll
        for (int rb = 0; rb < 2; ++rb)
#pragma unroll
            for (int ks = 0; ks < 4; ++ks)
                bv[rb][ks] = *(const long*)(&Bls[buf][boff[rb][ks]]);
#pragma unroll
        for (int ks = 0; ks < 4; ++ks)
            av[ks] = *(const long*)(&Als[buf][aoff[0][ks]]);
        if (t + 1 < nt) STAGE8(buf ^ 1, (t + 1) << 6);
        __builtin_amdgcn_s_setprio(1);
#pragma unroll
        for (int ks = 0; ks < 4; ++ks)
#pragma unroll
            for (int tj = 0; tj < 2; ++tj)
                acc[0][tj] = __builtin_amdgcn_mfma_f32_32x32x16_fp8_fp8(
                    av[ks], bv[tj][ks], acc[0][tj], 0, 0, 0);
        __builtin_amdgcn_s_setprio(0);
        // A rowblock 1 (bv reused)
#pragma unroll
        for (int ks = 0; ks < 4; ++ks)
            av[ks] = *(const long*)(&Als[buf][aoff[1][ks]]);
        __builtin_amdgcn_s_setprio(1);
#pragma unroll
        for (int ks = 0; ks < 4; ++ks)
#pragma unroll
            for (int tj = 0; tj < 2; ++tj)
                acc[1][tj] = __builtin_amdgcn_mfma_f32_32x32x16_fp8_fp8(
                    av[ks], bv[tj][ks], acc[1][tj], 0, 0, 0);
        __builtin_amdgcn_s_setprio(0);
        __syncthreads();
    }

    // epilogue: unscale + bias + gelu; store fp8 or bf16
#pragma unroll
    for (int ti = 0; ti < 2; ++ti) {
#pragma unroll
        for (int tj = 0; tj < 2; ++tj) {
            int n = n0 + wc * 64 + tj * 32 + l31;
            float bs = bias[n];
#pragma unroll
            for (int reg = 0; reg < 16; ++reg) {
                int row = (reg & 3) + 8 * (reg >> 2) + 4 * fq2;
                int m = m0 + wr * 64 + ti * 32 + row;
                float v = gelu_fast(fmaf(acc[ti][tj][reg], INV_WSCALE, bs));
                if (OUTFP8) C8[(size_t)m * N + n] = f2e4m3(v);
                else        Cb[(size_t)m * N + n] = __float2bfloat16(v);
            }
        }
    }
#undef STAGE8
}

// ============ 128x128 BK=64 FP8 GEMM, 16x16 MFMA (R15 core) — layer 2 ============
template <int OUTFP8>
__global__ __launch_bounds__(256, 2) void gemm128f8_kernel(
    const unsigned char* __restrict__ A,
    const unsigned char* __restrict__ Wt,
    const float* __restrict__ bias,
    unsigned char* __restrict__ C8,
    __hip_bfloat16* __restrict__ Cb,
    int K, int N) {
    __shared__ __align__(16) unsigned char Als[2][128 * 64];
    __shared__ __align__(16) unsigned char Bls[2][128 * 64];
    const int tid = threadIdx.x;
    const int wave = tid >> 6, lane = tid & 63;
    const int m0 = blockIdx.x * 128, n0 = blockIdx.y * 128;
    const int wr = wave >> 1, wc = wave & 1;
    const int fr = lane & 15, fq = lane >> 4;

    int sr[2], skel[2], sbase[2];
#pragma unroll
    for (int j = 0; j < 2; ++j) {
        int c = j * 256 + tid;
        int row = c >> 2;
        int inner = (c & 3) * 16;
        skel[j] = inner ^ ((row & 6) << 3);
        sr[j] = row;
        sbase[j] = (j * 256 + wave * 64) * 16;
    }
    int aoff[4], boff[4];
#pragma unroll
    for (int f = 0; f < 4; ++f) {
        int rA = wr * 64 + f * 16 + fr;
        aoff[f] = rA * 64 + ((fq * 8) ^ ((rA & 6) << 3));
        int rB = wc * 64 + f * 16 + fr;
        boff[f] = rB * 64 + ((fq * 8) ^ ((rB & 6) << 3));
    }

    f32x4 acc[4][4] = {};
    long av[4], bv[4];

#define STAGE8(bufn, kt) do {                                                         \
    _Pragma("unroll") for (int j = 0; j < 2; ++j) {                                   \
        GLD_LDS16(A + (size_t)(m0 + sr[j]) * K + (kt) + skel[j], (char*)Als[bufn] + sbase[j]); \
        GLD_LDS16(Wt + (size_t)(n0 + sr[j]) * K + (kt) + skel[j], (char*)Bls[bufn] + sbase[j]); \
    }                                                                                 \
} while (0)

    STAGE8(0, 0);
    __syncthreads();

    const int nt = K >> 6;
    for (int t = 0; t < nt; ++t) {
        const int buf = t & 1;
#pragma unroll
        for (int f = 0; f < 4; ++f) bv[f] = *(const long*)(&Bls[buf][boff[f]]);
#pragma unroll
        for (int f = 0; f < 4; ++f) av[f] = *(const long*)(&Als[buf][aoff[f]]);
        if (t + 1 < nt) STAGE8(buf ^ 1, (t + 1) << 6);
        __builtin_amdgcn_s_setprio(1);
#pragma unroll
        for (int mi = 0; mi < 4; ++mi)
#pragma unroll
            for (int ni = 0; ni < 4; ++ni)
                acc[mi][ni] = __builtin_amdgcn_mfma_f32_16x16x32_fp8_fp8(
                    av[mi], bv[ni], acc[mi][ni], 0, 0, 0);
        __builtin_amdgcn_s_setprio(0);
#pragma unroll
        for (int f = 0; f < 4; ++f) bv[f] = *(const long*)(&Bls[buf][boff[f] ^ 32]);
#pragma unroll
        for (int f = 0; f < 4; ++f) av[f] = *(const long*)(&Als[buf][aoff[f] ^ 32]);
        __builtin_amdgcn_s_setprio(1);
#pragma unroll
        for (int mi = 0; mi < 4; ++mi)
#pragma unroll
            for (int ni = 0; ni < 4; ++ni)
                acc[mi][ni] = __builtin_amdgcn_mfma_f32_16x16x32_fp8_fp8(
                    av[mi], bv[ni], acc[mi][ni], 0, 0, 0);
        __builtin_amdgcn_s_setprio(0);
        __syncthreads();
    }

#pragma unroll
    for (int mi = 0; mi < 4; ++mi) {
#pragma unroll
        for (int ni = 0; ni < 4; ++ni) {
            int n = n0 + wc * 64 + ni * 16 + fr;
            float bs = bias[n];
#pragma unroll
            for (int r = 0; r < 4; ++r) {
                int m = m0 + wr * 64 + mi * 16 + fq * 4 + r;
                float v = gelu_fast(fmaf(acc[mi][ni][r], INV_WSCALE, bs));
                if (OUTFP8) C8[(size_t)m * N + n] = f2e4m3(v);
                else        Cb[(size_t)m * N + n] = __float2bfloat16(v);
            }
        }
    }
#undef STAGE8
}

// ============ FP8 GEMM (layer 3, 16x16) + fused tf partial-dot ============
__global__ __launch_bounds__(256, 2) void gemm128f8_pdot_kernel(
    const unsigned char* __restrict__ A,
    const unsigned char* __restrict__ Wt,
    const float* __restrict__ bias,
    const float* __restrict__ w4,
    float* __restrict__ pdot,   // [M][2]
    int K, int N) {
    __shared__ __align__(16) unsigned char Als[2][128 * 64];
    __shared__ __align__(16) unsigned char Bls[2][128 * 64];
    __shared__ float spd[128][2];
    const int tid = threadIdx.x;
    const int wave = tid >> 6, lane = tid & 63;
    const int m0 = blockIdx.x * 128, n0 = blockIdx.y * 128;
    const int nb = blockIdx.y;
    const int wr = wave >> 1, wc = wave & 1;
    const int fr = lane & 15, fq = lane >> 4;

    int sr[2], skel[2], sbase[2];
#pragma unroll
    for (int j = 0; j < 2; ++j) {
        int c = j * 256 + tid;
        int row = c >> 2;
        int inner = (c & 3) * 16;
        skel[j] = inner ^ ((row & 6) << 3);
        sr[j] = row;
        sbase[j] = (j * 256 + wave * 64) * 16;
    }
    int aoff[4], boff[4];
#pragma unroll
    for (int f = 0; f < 4; ++f) {
        int rA = wr * 64 + f * 16 + fr;
        aoff[f] = rA * 64 + ((fq * 8) ^ ((rA & 6) << 3));
        int rB = wc * 64 + f * 16 + fr;
        boff[f] = rB * 64 + ((fq * 8) ^ ((rB & 6) << 3));
    }

    f32x4 acc[4][4] = {};
    long av[4], bv[4];

#define STAGE8(bufn, kt) do {                                                         \
    _Pragma("unroll") for (int j = 0; j < 2; ++j) {                                   \
        GLD_LDS16(A + (size_t)(m0 + sr[j]) * K + (kt) + skel[j], (char*)Als[bufn] + sbase[j]); \
        GLD_LDS16(Wt + (size_t)(n0 + sr[j]) * K + (kt) + skel[j], (char*)Bls[bufn] + sbase[j]); \
    }                                                                                 \
} while (0)

    STAGE8(0, 0);
    __syncthreads();

    const int nt = K >> 6;
    for (int t = 0; t < nt; ++t) {
        const int buf = t & 1;
#pragma unroll
        for (int f = 0; f < 4; ++f) bv[f] = *(const long*)(&Bls[buf][boff[f]]);
#pragma unroll
        for (int f = 0; f < 4; ++f) av[f] = *(const long*)(&Als[buf][aoff[f]]);
        if (t + 1 < nt) STAGE8(buf ^ 1, (t + 1) << 6);
        __builtin_amdgcn_s_setprio(1);
#pragma unroll
        for (int mi = 0; mi < 4; ++mi)
#pragma unroll
            for (int ni = 0; ni < 4; ++ni)
                acc[mi][ni] = __builtin_amdgcn_mfma_f32_16x16x32_fp8_fp8(
                    av[mi], bv[ni], acc[mi][ni], 0, 0, 0);
        __builtin_amdgcn_s_setprio(0);
#pragma unroll
        for (int f = 0; f < 4; ++f) bv[f] = *(const long*)(&Bls[buf][boff[f] ^ 32]);
#pragma unroll
        for (int f = 0; f < 4; ++f) av[f] = *(const long*)(&Als[buf][aoff[f] ^ 32]);
        __builtin_amdgcn_s_setprio(1);
#pragma unroll
        for (int mi = 0; mi < 4; ++mi)
#pragma unroll
            for (int ni = 0; ni < 4; ++ni)
                acc[mi][ni] = __builtin_amdgcn_mfma_f32_16x16x32_fp8_fp8(
                    av[mi], bv[ni], acc[mi][ni], 0, 0, 0);
        __builtin_amdgcn_s_setprio(0);
        __syncthreads();
    }

    // per-row partial dot over this block's 128 columns (deterministic)
    float pd[4][4];
#pragma unroll
    for (int mi = 0; mi < 4; ++mi)
#pragma unroll
        for (int r = 0; r < 4; ++r) {
            float s = 0.f;
#pragma unroll
            for (int ni = 0; ni < 4; ++ni) {
                int n = n0 + wc * 64 + ni * 16 + fr;
                s += gelu_fast(fmaf(acc[mi][ni][r], INV_WSCALE, bias[n])) * w4[n];
            }
            pd[mi][r] = s;
        }
#pragma unroll
    for (int off = 1; off < 16; off <<= 1)
#pragma unroll
        for (int mi = 0; mi < 4; ++mi)
#pragma unroll
            for (int r = 0; r < 4; ++r)
                pd[mi][r] += __shfl_xor(pd[mi][r], off);
    if (fr == 0) {
#pragma unroll
        for (int mi = 0; mi < 4; ++mi)
#pragma unroll
            for (int r = 0; r < 4; ++r)
                spd[wr * 64 + mi * 16 + fq * 4 + r][wc] = pd[mi][r];
    }
    __syncthreads();
    if (tid < 128) pdot[(size_t)(m0 + tid) * 2 + nb] = spd[tid][0] + spd[tid][1];
#undef STAGE8
}

// ---------------- tf + coupling + twist update; bf16 state, fp8 operand copy ----------------
__global__ __launch_bounds__(256) void tf_update_kernel(
    const float* __restrict__ srcf, const __hip_bfloat16* __restrict__ srcb, int use_bf,
    const float* __restrict__ pdot,  // [ROWS][2]
    const float* __restrict__ b4,
    const float* __restrict__ gf, const float* __restrict__ arp,
    float* __restrict__ out, __hip_bfloat16* __restrict__ outb,
    unsigned char* __restrict__ outb8, int wf, int wb, int w8) {
    const int wid = threadIdx.x >> 6, lane = threadIdx.x & 63;
    const int r = blockIdx.x * 4 + wid;
    const int b = r >> 12;  // S = 4096 rows per batch

    float2 pv = reinterpret_cast<const float2*>(pdot)[r];
    float tf = sigmf_(pv.x + pv.y + b4[0]);
    float comb = 0.7f * gf[b] + 0.3f * tf;
    float c = BASE_COUPLING + arp[0] * (comb - 0.5f) * 2.0f;

    float4 o_r, o_i, p_r, p_i;
    if (use_bf) {
        const uint2* s2 = reinterpret_cast<const uint2*>(srcb + (size_t)r * PD);
        o_r = ubf2f4(s2[lane]);
        o_i = ubf2f4(s2[64 + lane]);
        p_r = ubf2f4(s2[128 + lane]);
        p_i = ubf2f4(s2[192 + lane]);
    } else {
        const float4* s4 = reinterpret_cast<const float4*>(srcf + (size_t)r * PD);
        o_r = s4[lane];
        o_i = s4[64 + lane];
        p_r = s4[128 + lane];
        p_i = s4[192 + lane];
    }
    float4 n0 = axpy4(o_r, c, p_r);
    float4 n1 = axpy4(o_i, -c, p_i);
    float4 n2 = axpy4(p_r, -c, o_r);
    float4 n3 = axpy4(p_i, c, o_i);
    if (wf) {
        float4* row4 = reinterpret_cast<float4*>(out + (size_t)r * PD);
        row4[lane] = n0;
        row4[64 + lane] = n1;
        row4[128 + lane] = n2;
        row4[192 + lane] = n3;
    }
    if (wb) {
        uint2* rb4 = reinterpret_cast<uint2*>(outb + (size_t)r * PD);
        rb4[lane] = pk4(n0);
        rb4[64 + lane] = pk4(n1);
        rb4[128 + lane] = pk4(n2);
        rb4[192 + lane] = pk4(n3);
    }
    if (w8) {
        unsigned int* r8 = reinterpret_cast<unsigned int*>(outb8 + (size_t)r * PD);
        r8[lane] = pk8(n0);
        r8[64 + lane] = pk8(n1);
        r8[128 + lane] = pk8(n2);
        r8[192 + lane] = pk8(n3);
    }
}

// ---------------- launch ----------------
extern "C" void kernel_launch(void* const* d_in, const int* in_sizes, int n_in,
                              void* d_out, int out_size, void* d_ws, size_t ws_size,
                              hipStream_t stream) {
    const float* x     = (const float*)d_in[0];
    const float* cn_w1 = (const float*)d_in[1];
    const float* cn_b1 = (const float*)d_in[2];
    const float* cn_w2 = (const float*)d_in[3];
    const float* cn_b2 = (const float*)d_in[4];
    const float* cn_w3 = (const float*)d_in[5];
    const float* cn_b3 = (const float*)d_in[6];
    const float* cn_w4 = (const float*)d_in[7];
    const float* cn_b4 = (const float*)d_in[8];
    const float* gc_w1 = (const float*)d_in[9];
    const float* gc_b1 = (const float*)d_in[10];
    const float* gc_w2 = (const float*)d_in[11];
    const float* gc_b2 = (const float*)d_in[12];
    const float* gc_w3 = (const float*)d_in[13];
    const float* gc_b3 = (const float*)d_in[14];
    const float* ar    = (const float*)d_in[15];

    float* out = (float*)d_out;

    // workspace layout (~80 MB)
    char* ws = (char*)d_ws;
    unsigned char* h1_8   = (unsigned char*)(ws);                                   // 16 MB
    unsigned char* h2_8   = (unsigned char*)(ws + ((size_t)16 << 20));              // 8 MB
    __hip_bfloat16* outb  = (__hip_bfloat16*)(ws + ((size_t)24 << 20));             // 32 MB (bf16 state)
    unsigned char* outb8  = (unsigned char*)(ws + ((size_t)56 << 20));              // 16 MB (fp8 operand)
    unsigned char* wt1_8  = (unsigned char*)(ws + ((size_t)72 << 20));              // 1 MB
    unsigned char* wt2_8  = (unsigned char*)(ws + ((size_t)73 << 20));              // 0.5 MB
    unsigned char* wt3_8  = (unsigned char*)(ws + ((size_t)73 << 20) + ((size_t)1 << 19)); // 128 KB
    float* pdot           = (float*)(ws + ((size_t)74 << 20));                      // 128 KB
    float* part           = (float*)(ws + ((size_t)75 << 20));                      // 2 MB
    float* gc             = (float*)(ws + ((size_t)77 << 20));                      // small
    float* g1             = gc + 4 * PD;
    float* g2             = g1 + 4 * 512;
    float* gf             = g2 + 4 * 256;

    // weights -> fp8 (scaled x256)
    transpose_w8_kernel<<<dim3(32, 32), 256, 0, stream>>>(cn_w1, wt1_8, 1024, 1024);
    transpose_w8_kernel<<<dim3(32, 16), 256, 0, stream>>>(cn_w2, wt2_8, 1024, 512);
    transpose_w8_kernel<<<dim3(16, 8), 256, 0, stream>>>(cn_w3, wt3_8, 512, 256);

    copy_mean_cvt_kernel<<<512, 256, 0, stream>>>(x, outb8, part);
    mean_stage2<<<PB, 256, 0, stream>>>(part, gc);

    gn1_kernel<<<dim3(PB, 8), 256, 0, stream>>>(gc, gc_w1, gc_b1, g1);
    gn2_kernel<<<dim3(PB, 4), 256, 0, stream>>>(g1, gc_w2, gc_b2, g2);
    gn3_kernel<<<PB, 256, 0, stream>>>(g2, gc_w3, gc_b3, gf);

    for (int cyc = 0; cyc < NUM_CYCLES; ++cyc) {
        // L1: fp8 32x32 MFMA, fp8 out
        gemm128f8x32_kernel<1><<<dim3(128, 8), 256, 0, stream>>>(
            outb8, wt1_8, cn_b1, h1_8, nullptr, 1024, 1024);
        // L2: fp8 16x16 MFMA, fp8 out
        gemm128f8_kernel<1><<<dim3(128, 4), 256, 0, stream>>>(
            h1_8, wt2_8, cn_b2, h2_8, nullptr, 1024, 512);
        // L3: fp8 16x16 MFMA, fused pdot
        gemm128f8_pdot_kernel<<<dim3(128, 2), 256, 0, stream>>>(
            h2_8, wt3_8, cn_b3, cn_w4, pdot, 512, 256);
        int last = (cyc + 1 == NUM_CYCLES);
        tf_update_kernel<<<ROWS / 4, 256, 0, stream>>>(
            x, outb, (cyc > 0) ? 1 : 0, pdot, cn_b4, gf, ar,
            out, outb, outb8, last ? 1 : 0, last ? 0 : 1, last ? 0 : 1);
    }
}

// Round 17
// 333.856 us; speedup vs baseline: 1.0409x; 1.0409x over previous
//
#include <hip/hip_runtime.h>
#include <hip/hip_bf16.h>

// Problem constants (AdaptiveMobiusLayer): B=4, S=4096, DIM=1024
#define PB 4
#define PS 4096
#define PD 1024
#define ROWS (PB * PS)          // 16384
#define NUM_CYCLES 3
#define BASE_COUPLING 0.1f
#define WSCALE 256.0f           // weight scale for fp8 (w std 1/32 -> 8)
#define INV_WSCALE (1.0f / 256.0f)

typedef __attribute__((ext_vector_type(8))) short bf16x8;
typedef __attribute__((ext_vector_type(4))) float f32x4;

// ---------------- helpers ----------------
__device__ __forceinline__ float geluf(float x) {
    return 0.5f * x * (1.0f + erff(x * 0.70710678118654752440f));
}
__device__ __forceinline__ float gelu_fast(float x) {
    float u = (x + 0.044715f * x * x * x) * 2.3022077f;  // 2*0.7978845608*log2(e)
    return x * __builtin_amdgcn_rcpf(1.0f + exp2f(-u));
}
__device__ __forceinline__ float sigmf_(float x) {
    return 1.0f / (1.0f + expf(-x));
}
__device__ __forceinline__ uint2 pk4(float4 v) {
    __hip_bfloat16 h[4] = {__float2bfloat16(v.x), __float2bfloat16(v.y),
                           __float2bfloat16(v.z), __float2bfloat16(v.w)};
    return *reinterpret_cast<uint2*>(h);
}
__device__ __forceinline__ float4 axpy4(float4 a, float s, float4 b) {
    return make_float4(fmaf(s, b.x, a.x), fmaf(s, b.y, a.y),
                       fmaf(s, b.z, a.z), fmaf(s, b.w, a.w));
}
__device__ __forceinline__ float bf2f(unsigned short u) {
    unsigned int w = ((unsigned int)u) << 16;
    return __builtin_bit_cast(float, w);
}
__device__ __forceinline__ float4 ubf2f4(uint2 u) {
    unsigned short h[4];
    *reinterpret_cast<uint2*>(h) = u;
    return make_float4(bf2f(h[0]), bf2f(h[1]), bf2f(h[2]), bf2f(h[3]));
}
// manual e4m3fn encode: RNE, FTZ below 2^-6, saturate to 448 (0x7E)
__device__ __forceinline__ unsigned char f2e4m3(float x) {
    unsigned int u = __builtin_bit_cast(unsigned int, x);
    unsigned int s = (u >> 24) & 0x80u;
    float ax = __builtin_fabsf(x);
    if (!(ax >= 0.015625f)) return (unsigned char)s;      // FTZ + NaN->0
    if (ax >= 464.0f) return (unsigned char)(s | 0x7Eu);  // saturate
    unsigned int au = u & 0x7FFFFFFFu;
    unsigned int lsb = (au >> 20) & 1u;
    au += 0x0007FFFFu + lsb;                              // RNE to 3 mantissa bits
    unsigned int e = (au >> 23) - 127u + 7u;
    unsigned int m = (au >> 20) & 7u;
    if (e >= 16u) return (unsigned char)(s | 0x7Eu);
    return (unsigned char)(s | (e << 3) | m);
}
__device__ __forceinline__ unsigned int pk8(float4 v) {
    return (unsigned int)f2e4m3(v.x) | ((unsigned int)f2e4m3(v.y) << 8) |
           ((unsigned int)f2e4m3(v.z) << 16) | ((unsigned int)f2e4m3(v.w) << 24);
}

#define GLD_LDS16(gsrc, ldst)                                                        \
    __builtin_amdgcn_global_load_lds(                                                \
        (const __attribute__((address_space(1))) void*)(gsrc),                       \
        (__attribute__((address_space(3))) void*)(ldst), 16, 0, 0)

// ---------------- fused: outb8 = fp8(x) + partial mean over S ----------------
__global__ __launch_bounds__(256) void copy_mean_cvt_kernel(const float* __restrict__ x,
                                                            unsigned char* __restrict__ outb8,
                                                            float* __restrict__ part) {
    int b = blockIdx.x >> 7, sc = blockIdx.x & 127;
    size_t base = ((size_t)b * PS + (size_t)sc * 32) * PD;
    const float4* x4 = reinterpret_cast<const float4*>(x + base);
    unsigned int* o8 = reinterpret_cast<unsigned int*>(outb8 + base);
    int t = threadIdx.x;
    float4 acc = make_float4(0.f, 0.f, 0.f, 0.f);
    for (int r = 0; r < 32; ++r) {
        float4 v = x4[r * 256 + t];
        o8[r * 256 + t] = pk8(v);
        acc.x += v.x; acc.y += v.y; acc.z += v.z; acc.w += v.w;
    }
    reinterpret_cast<float4*>(part + ((size_t)(b * 128 + sc)) * PD)[t] = acc;
}

__global__ __launch_bounds__(256) void mean_stage2(const float* __restrict__ part,
                                                   float* __restrict__ gc) {
    int b = blockIdx.x, t = threadIdx.x;
    float4 s = make_float4(0.f, 0.f, 0.f, 0.f);
    for (int c = 0; c < 128; ++c) {
        float4 v = reinterpret_cast<const float4*>(part + ((size_t)(b * 128 + c)) * PD)[t];
        s.x += v.x; s.y += v.y; s.z += v.z; s.w += v.w;
    }
    s.x *= (1.0f / 4096.0f); s.y *= (1.0f / 4096.0f);
    s.z *= (1.0f / 4096.0f); s.w *= (1.0f / 4096.0f);
    reinterpret_cast<float4*>(gc + (size_t)b * PD)[t] = s;
}

// ---------------- weight transpose: W[K][N] f32 -> Wt8[N][K] fp8, scaled x256 ----------------
__global__ __launch_bounds__(256) void transpose_w8_kernel(const float* __restrict__ W,
                                                           unsigned char* __restrict__ Wt8,
                                                           int K, int N) {
    __shared__ float t[32][33];
    int k0 = blockIdx.x * 32, n0 = blockIdx.y * 32;
    int tx = threadIdx.x & 31, ty = threadIdx.x >> 5;
#pragma unroll
    for (int i = 0; i < 32; i += 8)
        t[ty + i][tx] = W[(size_t)(k0 + ty + i) * N + n0 + tx];
    __syncthreads();
#pragma unroll
    for (int i = 0; i < 32; i += 8)
        Wt8[(size_t)(n0 + ty + i) * K + k0 + tx] = f2e4m3(t[tx][ty + i] * WSCALE);
}

// ---------------- global context net, parallelized (f32, unchanged) ----------------
__global__ __launch_bounds__(256) void gn1_kernel(const float* __restrict__ gc,
                                                  const float* __restrict__ w1,
                                                  const float* __restrict__ b1,
                                                  float* __restrict__ g1) {
    __shared__ float gcs[1024];
    __shared__ float red[4][64];
    int b = blockIdx.x, j0 = blockIdx.y * 64;
    int t = threadIdx.x, wave = t >> 6, lane = t & 63;
    for (int i = t; i < 1024; i += 256) gcs[i] = gc[(size_t)b * PD + i];
    __syncthreads();
    int j = j0 + lane;
    float a = 0.f;
    int k0 = wave * 256;
    for (int k = k0; k < k0 + 256; ++k) a += gcs[k] * w1[(size_t)k * 512 + j];
    red[wave][lane] = a;
    __syncthreads();
    if (wave == 0) {
        float v = red[0][lane] + red[1][lane] + red[2][lane] + red[3][lane] + b1[j];
        g1[(size_t)b * 512 + j] = geluf(v);
    }
}

__global__ __launch_bounds__(256) void gn2_kernel(const float* __restrict__ g1,
                                                  const float* __restrict__ w2,
                                                  const float* __restrict__ b2,
                                                  float* __restrict__ g2) {
    __shared__ float g1s[512];
    __shared__ float red[4][64];
    int b = blockIdx.x, j0 = blockIdx.y * 64;
    int t = threadIdx.x, wave = t >> 6, lane = t & 63;
    for (int i = t; i < 512; i += 256) g1s[i] = g1[(size_t)b * 512 + i];
    __syncthreads();
    int j = j0 + lane;
    float a = 0.f;
    int k0 = wave * 128;
    for (int k = k0; k < k0 + 128; ++k) a += g1s[k] * w2[(size_t)k * 256 + j];
    red[wave][lane] = a;
    __syncthreads();
    if (wave == 0) {
        float v = red[0][lane] + red[1][lane] + red[2][lane] + red[3][lane] + b2[j];
        g2[(size_t)b * 256 + j] = geluf(v);
    }
}

__global__ __launch_bounds__(256) void gn3_kernel(const float* __restrict__ g2,
                                                  const float* __restrict__ w3,
                                                  const float* __restrict__ b3,
                                                  float* __restrict__ gf) {
    __shared__ float red[256];
    int b = blockIdx.x, t = threadIdx.x;
    red[t] = g2[(size_t)b * 256 + t] * w3[t];
    __syncthreads();
    for (int s = 128; s > 0; s >>= 1) {
        if (t < s) red[t] += red[t + s];
        __syncthreads();
    }
    if (t == 0) gf[b] = sigmf_(red[0] + b3[0]);
}

// ============ 128x128 BK=64 FP8 GEMM, 16x16x32 MFMA (measured-best core) ============
// C[m][n] = gelu((sum_k A[m][k]*Wt[n][k]) * INV_WSCALE + bias[n]).
// 256 thr = 4 waves (2x2), wave 64x64. LDS 32 KB dbuf; 2 blocks/CU.
// 16B-granular swizzle byte ^= ((row&6)<<3), both sides (rule 21).
template <int OUTFP8>
__global__ __launch_bounds__(256, 2) void gemm128f8_kernel(
    const unsigned char* __restrict__ A,
    const unsigned char* __restrict__ Wt,
    const float* __restrict__ bias,
    unsigned char* __restrict__ C8,
    __hip_bfloat16* __restrict__ Cb,
    int K, int N) {
    __shared__ __align__(16) unsigned char Als[2][128 * 64];
    __shared__ __align__(16) unsigned char Bls[2][128 * 64];
    const int tid = threadIdx.x;
    const int wave = tid >> 6, lane = tid & 63;
    const int m0 = blockIdx.x * 128, n0 = blockIdx.y * 128;
    const int wr = wave >> 1, wc = wave & 1;
    const int fr = lane & 15, fq = lane >> 4;

    int sr[2], skel[2], sbase[2];
#pragma unroll
    for (int j = 0; j < 2; ++j) {
        int c = j * 256 + tid;
        int row = c >> 2;
        int inner = (c & 3) * 16;
        skel[j] = inner ^ ((row & 6) << 3);
        sr[j] = row;
        sbase[j] = (j * 256 + wave * 64) * 16;
    }
    int aoff[4], boff[4];
#pragma unroll
    for (int f = 0; f < 4; ++f) {
        int rA = wr * 64 + f * 16 + fr;
        aoff[f] = rA * 64 + ((fq * 8) ^ ((rA & 6) << 3));
        int rB = wc * 64 + f * 16 + fr;
        boff[f] = rB * 64 + ((fq * 8) ^ ((rB & 6) << 3));
    }

    f32x4 acc[4][4] = {};
    long av[4], bv[4];

#define STAGE8(bufn, kt) do {                                                         \
    _Pragma("unroll") for (int j = 0; j < 2; ++j) {                                   \
        GLD_LDS16(A + (size_t)(m0 + sr[j]) * K + (kt) + skel[j], (char*)Als[bufn] + sbase[j]); \
        GLD_LDS16(Wt + (size_t)(n0 + sr[j]) * K + (kt) + skel[j], (char*)Bls[bufn] + sbase[j]); \
    }                                                                                 \
} while (0)

    STAGE8(0, 0);
    __syncthreads();

    const int nt = K >> 6;
    for (int t = 0; t < nt; ++t) {
        const int buf = t & 1;
#pragma unroll
        for (int f = 0; f < 4; ++f) bv[f] = *(const long*)(&Bls[buf][boff[f]]);
#pragma unroll
        for (int f = 0; f < 4; ++f) av[f] = *(const long*)(&Als[buf][aoff[f]]);
        if (t + 1 < nt) STAGE8(buf ^ 1, (t + 1) << 6);
        __builtin_amdgcn_s_setprio(1);
#pragma unroll
        for (int mi = 0; mi < 4; ++mi)
#pragma unroll
            for (int ni = 0; ni < 4; ++ni)
                acc[mi][ni] = __builtin_amdgcn_mfma_f32_16x16x32_fp8_fp8(
                    av[mi], bv[ni], acc[mi][ni], 0, 0, 0);
        __builtin_amdgcn_s_setprio(0);
#pragma unroll
        for (int f = 0; f < 4; ++f) bv[f] = *(const long*)(&Bls[buf][boff[f] ^ 32]);
#pragma unroll
        for (int f = 0; f < 4; ++f) av[f] = *(const long*)(&Als[buf][aoff[f] ^ 32]);
        __builtin_amdgcn_s_setprio(1);
#pragma unroll
        for (int mi = 0; mi < 4; ++mi)
#pragma unroll
            for (int ni = 0; ni < 4; ++ni)
                acc[mi][ni] = __builtin_amdgcn_mfma_f32_16x16x32_fp8_fp8(
                    av[mi], bv[ni], acc[mi][ni], 0, 0, 0);
        __builtin_amdgcn_s_setprio(0);
        __syncthreads();
    }

#pragma unroll
    for (int mi = 0; mi < 4; ++mi) {
#pragma unroll
        for (int ni = 0; ni < 4; ++ni) {
            int n = n0 + wc * 64 + ni * 16 + fr;
            float bs = bias[n];
#pragma unroll
            for (int r = 0; r < 4; ++r) {
                int m = m0 + wr * 64 + mi * 16 + fq * 4 + r;
                float v = gelu_fast(fmaf(acc[mi][ni][r], INV_WSCALE, bs));
                if (OUTFP8) C8[(size_t)m * N + n] = f2e4m3(v);
                else        Cb[(size_t)m * N + n] = __float2bfloat16(v);
            }
        }
    }
#undef STAGE8
}

// ============ FP8 GEMM (layer 3, 16x16) + fused tf partial-dot ============
__global__ __launch_bounds__(256, 2) void gemm128f8_pdot_kernel(
    const unsigned char* __restrict__ A,
    const unsigned char* __restrict__ Wt,
    const float* __restrict__ bias,
    const float* __restrict__ w4,
    float* __restrict__ pdot,   // [M][2]
    int K, int N) {
    __shared__ __align__(16) unsigned char Als[2][128 * 64];
    __shared__ __align__(16) unsigned char Bls[2][128 * 64];
    __shared__ float spd[128][2];
    const int tid = threadIdx.x;
    const int wave = tid >> 6, lane = tid & 63;
    const int m0 = blockIdx.x * 128, n0 = blockIdx.y * 128;
    const int nb = blockIdx.y;
    const int wr = wave >> 1, wc = wave & 1;
    const int fr = lane & 15, fq = lane >> 4;

    int sr[2], skel[2], sbase[2];
#pragma unroll
    for (int j = 0; j < 2; ++j) {
        int c = j * 256 + tid;
        int row = c >> 2;
        int inner = (c & 3) * 16;
        skel[j] = inner ^ ((row & 6) << 3);
        sr[j] = row;
        sbase[j] = (j * 256 + wave * 64) * 16;
    }
    int aoff[4], boff[4];
#pragma unroll
    for (int f = 0; f < 4; ++f) {
        int rA = wr * 64 + f * 16 + fr;
        aoff[f] = rA * 64 + ((fq * 8) ^ ((rA & 6) << 3));
        int rB = wc * 64 + f * 16 + fr;
        boff[f] = rB * 64 + ((fq * 8) ^ ((rB & 6) << 3));
    }

    f32x4 acc[4][4] = {};
    long av[4], bv[4];

#define STAGE8(bufn, kt) do {                                                         \
    _Pragma("unroll") for (int j = 0; j < 2; ++j) {                                   \
        GLD_LDS16(A + (size_t)(m0 + sr[j]) * K + (kt) + skel[j], (char*)Als[bufn] + sbase[j]); \
        GLD_LDS16(Wt + (size_t)(n0 + sr[j]) * K + (kt) + skel[j], (char*)Bls[bufn] + sbase[j]); \
    }                                                                                 \
} while (0)

    STAGE8(0, 0);
    __syncthreads();

    const int nt = K >> 6;
    for (int t = 0; t < nt; ++t) {
        const int buf = t & 1;
#pragma unroll
        for (int f = 0; f < 4; ++f) bv[f] = *(const long*)(&Bls[buf][boff[f]]);
#pragma unroll
        for (int f = 0; f < 4; ++f) av[f] = *(const long*)(&Als[buf][aoff[f]]);
        if (t + 1 < nt) STAGE8(buf ^ 1, (t + 1) << 6);
        __builtin_amdgcn_s_setprio(1);
#pragma unroll
        for (int mi = 0; mi < 4; ++mi)
#pragma unroll
            for (int ni = 0; ni < 4; ++ni)
                acc[mi][ni] = __builtin_amdgcn_mfma_f32_16x16x32_fp8_fp8(
                    av[mi], bv[ni], acc[mi][ni], 0, 0, 0);
        __builtin_amdgcn_s_setprio(0);
#pragma unroll
        for (int f = 0; f < 4; ++f) bv[f] = *(const long*)(&Bls[buf][boff[f] ^ 32]);
#pragma unroll
        for (int f = 0; f < 4; ++f) av[f] = *(const long*)(&Als[buf][aoff[f] ^ 32]);
        __builtin_amdgcn_s_setprio(1);
#pragma unroll
        for (int mi = 0; mi < 4; ++mi)
#pragma unroll
            for (int ni = 0; ni < 4; ++ni)
                acc[mi][ni] = __builtin_amdgcn_mfma_f32_16x16x32_fp8_fp8(
                    av[mi], bv[ni], acc[mi][ni], 0, 0, 0);
        __builtin_amdgcn_s_setprio(0);
        __syncthreads();
    }

    // per-row partial dot over this block's 128 columns (deterministic)
    float pd[4][4];
#pragma unroll
    for (int mi = 0; mi < 4; ++mi)
#pragma unroll
        for (int r = 0; r < 4; ++r) {
            float s = 0.f;
#pragma unroll
            for (int ni = 0; ni < 4; ++ni) {
                int n = n0 + wc * 64 + ni * 16 + fr;
                s += gelu_fast(fmaf(acc[mi][ni][r], INV_WSCALE, bias[n])) * w4[n];
            }
            pd[mi][r] = s;
        }
#pragma unroll
    for (int off = 1; off < 16; off <<= 1)
#pragma unroll
        for (int mi = 0; mi < 4; ++mi)
#pragma unroll
            for (int r = 0; r < 4; ++r)
                pd[mi][r] += __shfl_xor(pd[mi][r], off);
    if (fr == 0) {
#pragma unroll
        for (int mi = 0; mi < 4; ++mi)
#pragma unroll
            for (int r = 0; r < 4; ++r)
                spd[wr * 64 + mi * 16 + fq * 4 + r][wc] = pd[mi][r];
    }
    __syncthreads();
    if (tid < 128) pdot[(size_t)(m0 + tid) * 2 + nb] = spd[tid][0] + spd[tid][1];
#undef STAGE8
}

// ---------------- tf + coupling + twist update; bf16 state, fp8 operand copy ----------------
__global__ __launch_bounds__(256) void tf_update_kernel(
    const float* __restrict__ srcf, const __hip_bfloat16* __restrict__ srcb, int use_bf,
    const float* __restrict__ pdot,  // [ROWS][2]
    const float* __restrict__ b4,
    const float* __restrict__ gf, const float* __restrict__ arp,
    float* __restrict__ out, __hip_bfloat16* __restrict__ outb,
    unsigned char* __restrict__ outb8, int wf, int wb, int w8) {
    const int wid = threadIdx.x >> 6, lane = threadIdx.x & 63;
    const int r = blockIdx.x * 4 + wid;
    const int b = r >> 12;  // S = 4096 rows per batch

    float2 pv = reinterpret_cast<const float2*>(pdot)[r];
    float tf = sigmf_(pv.x + pv.y + b4[0]);
    float comb = 0.7f * gf[b] + 0.3f * tf;
    float c = BASE_COUPLING + arp[0] * (comb - 0.5f) * 2.0f;

    float4 o_r, o_i, p_r, p_i;
    if (use_bf) {
        const uint2* s2 = reinterpret_cast<const uint2*>(srcb + (size_t)r * PD);
        o_r = ubf2f4(s2[lane]);
        o_i = ubf2f4(s2[64 + lane]);
        p_r = ubf2f4(s2[128 + lane]);
        p_i = ubf2f4(s2[192 + lane]);
    } else {
        const float4* s4 = reinterpret_cast<const float4*>(srcf + (size_t)r * PD);
        o_r = s4[lane];
        o_i = s4[64 + lane];
        p_r = s4[128 + lane];
        p_i = s4[192 + lane];
    }
    float4 n0 = axpy4(o_r, c, p_r);
    float4 n1 = axpy4(o_i, -c, p_i);
    float4 n2 = axpy4(p_r, -c, o_r);
    float4 n3 = axpy4(p_i, c, o_i);
    if (wf) {
        float4* row4 = reinterpret_cast<float4*>(out + (size_t)r * PD);
        row4[lane] = n0;
        row4[64 + lane] = n1;
        row4[128 + lane] = n2;
        row4[192 + lane] = n3;
    }
    if (wb) {
        uint2* rb4 = reinterpret_cast<uint2*>(outb + (size_t)r * PD);
        rb4[lane] = pk4(n0);
        rb4[64 + lane] = pk4(n1);
        rb4[128 + lane] = pk4(n2);
        rb4[192 + lane] = pk4(n3);
    }
    if (w8) {
        unsigned int* r8 = reinterpret_cast<unsigned int*>(outb8 + (size_t)r * PD);
        r8[lane] = pk8(n0);
        r8[64 + lane] = pk8(n1);
        r8[128 + lane] = pk8(n2);
        r8[192 + lane] = pk8(n3);
    }
}

// ---------------- launch ----------------
extern "C" void kernel_launch(void* const* d_in, const int* in_sizes, int n_in,
                              void* d_out, int out_size, void* d_ws, size_t ws_size,
                              hipStream_t stream) {
    const float* x     = (const float*)d_in[0];
    const float* cn_w1 = (const float*)d_in[1];
    const float* cn_b1 = (const float*)d_in[2];
    const float* cn_w2 = (const float*)d_in[3];
    const float* cn_b2 = (const float*)d_in[4];
    const float* cn_w3 = (const float*)d_in[5];
    const float* cn_b3 = (const float*)d_in[6];
    const float* cn_w4 = (const float*)d_in[7];
    const float* cn_b4 = (const float*)d_in[8];
    const float* gc_w1 = (const float*)d_in[9];
    const float* gc_b1 = (const float*)d_in[10];
    const float* gc_w2 = (const float*)d_in[11];
    const float* gc_b2 = (const float*)d_in[12];
    const float* gc_w3 = (const float*)d_in[13];
    const float* gc_b3 = (const float*)d_in[14];
    const float* ar    = (const float*)d_in[15];

    float* out = (float*)d_out;

    // workspace layout (~80 MB)
    char* ws = (char*)d_ws;
    unsigned char* h1_8   = (unsigned char*)(ws);                                   // 16 MB
    unsigned char* h2_8   = (unsigned char*)(ws + ((size_t)16 << 20));              // 8 MB
    __hip_bfloat16* outb  = (__hip_bfloat16*)(ws + ((size_t)24 << 20));             // 32 MB (bf16 state)
    unsigned char* outb8  = (unsigned char*)(ws + ((size_t)56 << 20));              // 16 MB (fp8 operand)
    unsigned char* wt1_8  = (unsigned char*)(ws + ((size_t)72 << 20));              // 1 MB
    unsigned char* wt2_8  = (unsigned char*)(ws + ((size_t)73 << 20));              // 0.5 MB
    unsigned char* wt3_8  = (unsigned char*)(ws + ((size_t)73 << 20) + ((size_t)1 << 19)); // 128 KB
    float* pdot           = (float*)(ws + ((size_t)74 << 20));                      // 128 KB
    float* part           = (float*)(ws + ((size_t)75 << 20));                      // 2 MB
    float* gc             = (float*)(ws + ((size_t)77 << 20));                      // small
    float* g1             = gc + 4 * PD;
    float* g2             = g1 + 4 * 512;
    float* gf             = g2 + 4 * 256;

    // weights -> fp8 (scaled x256)
    transpose_w8_kernel<<<dim3(32, 32), 256, 0, stream>>>(cn_w1, wt1_8, 1024, 1024);
    transpose_w8_kernel<<<dim3(32, 16), 256, 0, stream>>>(cn_w2, wt2_8, 1024, 512);
    transpose_w8_kernel<<<dim3(16, 8), 256, 0, stream>>>(cn_w3, wt3_8, 512, 256);

    copy_mean_cvt_kernel<<<512, 256, 0, stream>>>(x, outb8, part);
    mean_stage2<<<PB, 256, 0, stream>>>(part, gc);

    gn1_kernel<<<dim3(PB, 8), 256, 0, stream>>>(gc, gc_w1, gc_b1, g1);
    gn2_kernel<<<dim3(PB, 4), 256, 0, stream>>>(g1, gc_w2, gc_b2, g2);
    gn3_kernel<<<PB, 256, 0, stream>>>(g2, gc_w3, gc_b3, gf);

    for (int cyc = 0; cyc < NUM_CYCLES; ++cyc) {
        // L1: fp8 16x16 MFMA (measured-best), fp8 out
        gemm128f8_kernel<1><<<dim3(128, 8), 256, 0, stream>>>(
            outb8, wt1_8, cn_b1, h1_8, nullptr, 1024, 1024);
        // L2: fp8 16x16 MFMA, fp8 out
        gemm128f8_kernel<1><<<dim3(128, 4), 256, 0, stream>>>(
            h1_8, wt2_8, cn_b2, h2_8, nullptr, 1024, 512);
        // L3: fp8 16x16 MFMA, fused pdot
        gemm128f8_pdot_kernel<<<dim3(128, 2), 256, 0, stream>>>(
            h2_8, wt3_8, cn_b3, cn_w4, pdot, 512, 256);
        int last = (cyc + 1 == NUM_CYCLES);
        tf_update_kernel<<<ROWS / 4, 256, 0, stream>>>(
            x, outb, (cyc > 0) ? 1 : 0, pdot, cn_b4, gf, ar,
            out, outb, outb8, last ? 1 : 0, last ? 0 : 1, last ? 0 : 1);
    }
}

// Round 18
// 277.727 us; speedup vs baseline: 1.2512x; 1.2021x over previous
//
#include <hip/hip_runtime.h>
#include <hip/hip_bf16.h>

// Problem constants (AdaptiveMobiusLayer): B=4, S=4096, DIM=1024
#define PB 4
#define PS 4096
#define PD 1024
#define ROWS (PB * PS)          // 16384
#define NUM_CYCLES 3
#define BASE_COUPLING 0.1f
#define WSCALE 256.0f           // weight scale for fp8 (w std 1/32 -> 8)
#define INV_WSCALE (1.0f / 256.0f)

typedef __attribute__((ext_vector_type(8))) short bf16x8;
typedef __attribute__((ext_vector_type(4))) float f32x4;

// ---------------- helpers ----------------
__device__ __forceinline__ float geluf(float x) {
    return 0.5f * x * (1.0f + erff(x * 0.70710678118654752440f));
}
__device__ __forceinline__ float gelu_fast(float x) {
    float u = (x + 0.044715f * x * x * x) * 2.3022077f;  // 2*0.7978845608*log2(e)
    return x * __builtin_amdgcn_rcpf(1.0f + exp2f(-u));
}
__device__ __forceinline__ float sigmf_(float x) {
    return 1.0f / (1.0f + expf(-x));
}
__device__ __forceinline__ uint2 pk4(float4 v) {
    __hip_bfloat16 h[4] = {__float2bfloat16(v.x), __float2bfloat16(v.y),
                           __float2bfloat16(v.z), __float2bfloat16(v.w)};
    return *reinterpret_cast<uint2*>(h);
}
__device__ __forceinline__ float4 axpy4(float4 a, float s, float4 b) {
    return make_float4(fmaf(s, b.x, a.x), fmaf(s, b.y, a.y),
                       fmaf(s, b.z, a.z), fmaf(s, b.w, a.w));
}
__device__ __forceinline__ float bf2f(unsigned short u) {
    unsigned int w = ((unsigned int)u) << 16;
    return __builtin_bit_cast(float, w);
}
__device__ __forceinline__ float4 ubf2f4(uint2 u) {
    unsigned short h[4];
    *reinterpret_cast<uint2*>(h) = u;
    return make_float4(bf2f(h[0]), bf2f(h[1]), bf2f(h[2]), bf2f(h[3]));
}
// manual e4m3fn encode (fallback): RNE, FTZ below 2^-6, saturate to 448
__device__ __forceinline__ unsigned char f2e4m3_sw(float x) {
    unsigned int u = __builtin_bit_cast(unsigned int, x);
    unsigned int s = (u >> 24) & 0x80u;
    float ax = __builtin_fabsf(x);
    if (!(ax >= 0.015625f)) return (unsigned char)s;
    if (ax >= 464.0f) return (unsigned char)(s | 0x7Eu);
    unsigned int au = u & 0x7FFFFFFFu;
    unsigned int lsb = (au >> 20) & 1u;
    au += 0x0007FFFFu + lsb;
    unsigned int e = (au >> 23) - 127u + 7u;
    unsigned int m = (au >> 20) & 7u;
    if (e >= 16u) return (unsigned char)(s | 0x7Eu);
    return (unsigned char)(s | (e << 3) | m);
}
#if __has_builtin(__builtin_amdgcn_cvt_pk_fp8_f32)
// HW packed fp8 encode: 2 instructions per 4 values (vs ~48 for the manual path)
__device__ __forceinline__ unsigned int pk8(float4 v) {
    int r = 0;
    r = __builtin_amdgcn_cvt_pk_fp8_f32(v.x, v.y, r, false);  // low 16 bits
    r = __builtin_amdgcn_cvt_pk_fp8_f32(v.z, v.w, r, true);   // high 16 bits
    return (unsigned int)r;
}
__device__ __forceinline__ unsigned char f2e4m3(float x) {
    return (unsigned char)(__builtin_amdgcn_cvt_pk_fp8_f32(x, x, 0, false) & 0xFF);
}
#else
__device__ __forceinline__ unsigned int pk8(float4 v) {
    return (unsigned int)f2e4m3_sw(v.x) | ((unsigned int)f2e4m3_sw(v.y) << 8) |
           ((unsigned int)f2e4m3_sw(v.z) << 16) | ((unsigned int)f2e4m3_sw(v.w) << 24);
}
__device__ __forceinline__ unsigned char f2e4m3(float x) { return f2e4m3_sw(x); }
#endif

#define GLD_LDS16(gsrc, ldst)                                                        \
    __builtin_amdgcn_global_load_lds(                                                \
        (const __attribute__((address_space(1))) void*)(gsrc),                       \
        (__attribute__((address_space(3))) void*)(ldst), 16, 0, 0)

// ---------------- fused: outb8 = fp8(x) + partial mean over S ----------------
__global__ __launch_bounds__(256) void copy_mean_cvt_kernel(const float* __restrict__ x,
                                                            unsigned char* __restrict__ outb8,
                                                            float* __restrict__ part) {
    int b = blockIdx.x >> 7, sc = blockIdx.x & 127;
    size_t base = ((size_t)b * PS + (size_t)sc * 32) * PD;
    const float4* x4 = reinterpret_cast<const float4*>(x + base);
    unsigned int* o8 = reinterpret_cast<unsigned int*>(outb8 + base);
    int t = threadIdx.x;
    float4 acc = make_float4(0.f, 0.f, 0.f, 0.f);
    for (int r = 0; r < 32; ++r) {
        float4 v = x4[r * 256 + t];
        o8[r * 256 + t] = pk8(v);
        acc.x += v.x; acc.y += v.y; acc.z += v.z; acc.w += v.w;
    }
    reinterpret_cast<float4*>(part + ((size_t)(b * 128 + sc)) * PD)[t] = acc;
}

__global__ __launch_bounds__(256) void mean_stage2(const float* __restrict__ part,
                                                   float* __restrict__ gc) {
    int b = blockIdx.x, t = threadIdx.x;
    float4 s = make_float4(0.f, 0.f, 0.f, 0.f);
    for (int c = 0; c < 128; ++c) {
        float4 v = reinterpret_cast<const float4*>(part + ((size_t)(b * 128 + c)) * PD)[t];
        s.x += v.x; s.y += v.y; s.z += v.z; s.w += v.w;
    }
    s.x *= (1.0f / 4096.0f); s.y *= (1.0f / 4096.0f);
    s.z *= (1.0f / 4096.0f); s.w *= (1.0f / 4096.0f);
    reinterpret_cast<float4*>(gc + (size_t)b * PD)[t] = s;
}

// ---------------- weight transpose: W[K][N] f32 -> Wt8[N][K] fp8, scaled x256 ----------------
__global__ __launch_bounds__(256) void transpose_w8_kernel(const float* __restrict__ W,
                                                           unsigned char* __restrict__ Wt8,
                                                           int K, int N) {
    __shared__ float t[32][33];
    int k0 = blockIdx.x * 32, n0 = blockIdx.y * 32;
    int tx = threadIdx.x & 31, ty = threadIdx.x >> 5;
#pragma unroll
    for (int i = 0; i < 32; i += 8)
        t[ty + i][tx] = W[(size_t)(k0 + ty + i) * N + n0 + tx];
    __syncthreads();
#pragma unroll
    for (int i = 0; i < 32; i += 8)
        Wt8[(size_t)(n0 + ty + i) * K + k0 + tx] = f2e4m3(t[tx][ty + i] * WSCALE);
}

// ---------------- global context net, parallelized (f32, unchanged) ----------------
__global__ __launch_bounds__(256) void gn1_kernel(const float* __restrict__ gc,
                                                  const float* __restrict__ w1,
                                                  const float* __restrict__ b1,
                                                  float* __restrict__ g1) {
    __shared__ float gcs[1024];
    __shared__ float red[4][64];
    int b = blockIdx.x, j0 = blockIdx.y * 64;
    int t = threadIdx.x, wave = t >> 6, lane = t & 63;
    for (int i = t; i < 1024; i += 256) gcs[i] = gc[(size_t)b * PD + i];
    __syncthreads();
    int j = j0 + lane;
    float a = 0.f;
    int k0 = wave * 256;
    for (int k = k0; k < k0 + 256; ++k) a += gcs[k] * w1[(size_t)k * 512 + j];
    red[wave][lane] = a;
    __syncthreads();
    if (wave == 0) {
        float v = red[0][lane] + red[1][lane] + red[2][lane] + red[3][lane] + b1[j];
        g1[(size_t)b * 512 + j] = geluf(v);
    }
}

__global__ __launch_bounds__(256) void gn2_kernel(const float* __restrict__ g1,
                                                  const float* __restrict__ w2,
                                                  const float* __restrict__ b2,
                                                  float* __restrict__ g2) {
    __shared__ float g1s[512];
    __shared__ float red[4][64];
    int b = blockIdx.x, j0 = blockIdx.y * 64;
    int t = threadIdx.x, wave = t >> 6, lane = t & 63;
    for (int i = t; i < 512; i += 256) g1s[i] = g1[(size_t)b * 512 + i];
    __syncthreads();
    int j = j0 + lane;
    float a = 0.f;
    int k0 = wave * 128;
    for (int k = k0; k < k0 + 128; ++k) a += g1s[k] * w2[(size_t)k * 256 + j];
    red[wave][lane] = a;
    __syncthreads();
    if (wave == 0) {
        float v = red[0][lane] + red[1][lane] + red[2][lane] + red[3][lane] + b2[j];
        g2[(size_t)b * 256 + j] = geluf(v);
    }
}

__global__ __launch_bounds__(256) void gn3_kernel(const float* __restrict__ g2,
                                                  const float* __restrict__ w3,
                                                  const float* __restrict__ b3,
                                                  float* __restrict__ gf) {
    __shared__ float red[256];
    int b = blockIdx.x, t = threadIdx.x;
    red[t] = g2[(size_t)b * 256 + t] * w3[t];
    __syncthreads();
    for (int s = 128; s > 0; s >>= 1) {
        if (t < s) red[t] += red[t + s];
        __syncthreads();
    }
    if (t == 0) gf[b] = sigmf_(red[0] + b3[0]);
}

// ============ 128x128 BK=64 FP8 GEMM, 16x16x32 MFMA (measured-best core) ============
template <int OUTFP8>
__global__ __launch_bounds__(256, 2) void gemm128f8_kernel(
    const unsigned char* __restrict__ A,
    const unsigned char* __restrict__ Wt,
    const float* __restrict__ bias,
    unsigned char* __restrict__ C8,
    __hip_bfloat16* __restrict__ Cb,
    int K, int N) {
    __shared__ __align__(16) unsigned char Als[2][128 * 64];
    __shared__ __align__(16) unsigned char Bls[2][128 * 64];
    const int tid = threadIdx.x;
    const int wave = tid >> 6, lane = tid & 63;
    const int m0 = blockIdx.x * 128, n0 = blockIdx.y * 128;
    const int wr = wave >> 1, wc = wave & 1;
    const int fr = lane & 15, fq = lane >> 4;

    int sr[2], skel[2], sbase[2];
#pragma unroll
    for (int j = 0; j < 2; ++j) {
        int c = j * 256 + tid;
        int row = c >> 2;
        int inner = (c & 3) * 16;
        skel[j] = inner ^ ((row & 6) << 3);
        sr[j] = row;
        sbase[j] = (j * 256 + wave * 64) * 16;
    }
    int aoff[4], boff[4];
#pragma unroll
    for (int f = 0; f < 4; ++f) {
        int rA = wr * 64 + f * 16 + fr;
        aoff[f] = rA * 64 + ((fq * 8) ^ ((rA & 6) << 3));
        int rB = wc * 64 + f * 16 + fr;
        boff[f] = rB * 64 + ((fq * 8) ^ ((rB & 6) << 3));
    }

    f32x4 acc[4][4] = {};
    long av[4], bv[4];

#define STAGE8(bufn, kt) do {                                                         \
    _Pragma("unroll") for (int j = 0; j < 2; ++j) {                                   \
        GLD_LDS16(A + (size_t)(m0 + sr[j]) * K + (kt) + skel[j], (char*)Als[bufn] + sbase[j]); \
        GLD_LDS16(Wt + (size_t)(n0 + sr[j]) * K + (kt) + skel[j], (char*)Bls[bufn] + sbase[j]); \
    }                                                                                 \
} while (0)

    STAGE8(0, 0);
    __syncthreads();

    const int nt = K >> 6;
    for (int t = 0; t < nt; ++t) {
        const int buf = t & 1;
#pragma unroll
        for (int f = 0; f < 4; ++f) bv[f] = *(const long*)(&Bls[buf][boff[f]]);
#pragma unroll
        for (int f = 0; f < 4; ++f) av[f] = *(const long*)(&Als[buf][aoff[f]]);
        if (t + 1 < nt) STAGE8(buf ^ 1, (t + 1) << 6);
        __builtin_amdgcn_s_setprio(1);
#pragma unroll
        for (int mi = 0; mi < 4; ++mi)
#pragma unroll
            for (int ni = 0; ni < 4; ++ni)
                acc[mi][ni] = __builtin_amdgcn_mfma_f32_16x16x32_fp8_fp8(
                    av[mi], bv[ni], acc[mi][ni], 0, 0, 0);
        __builtin_amdgcn_s_setprio(0);
#pragma unroll
        for (int f = 0; f < 4; ++f) bv[f] = *(const long*)(&Bls[buf][boff[f] ^ 32]);
#pragma unroll
        for (int f = 0; f < 4; ++f) av[f] = *(const long*)(&Als[buf][aoff[f] ^ 32]);
        __builtin_amdgcn_s_setprio(1);
#pragma unroll
        for (int mi = 0; mi < 4; ++mi)
#pragma unroll
            for (int ni = 0; ni < 4; ++ni)
                acc[mi][ni] = __builtin_amdgcn_mfma_f32_16x16x32_fp8_fp8(
                    av[mi], bv[ni], acc[mi][ni], 0, 0, 0);
        __builtin_amdgcn_s_setprio(0);
        __syncthreads();
    }

#pragma unroll
    for (int mi = 0; mi < 4; ++mi) {
#pragma unroll
        for (int ni = 0; ni < 4; ++ni) {
            int n = n0 + wc * 64 + ni * 16 + fr;
            float bs = bias[n];
#pragma unroll
            for (int r = 0; r < 4; ++r) {
                int m = m0 + wr * 64 + mi * 16 + fq * 4 + r;
                float v = gelu_fast(fmaf(acc[mi][ni][r], INV_WSCALE, bs));
                if (OUTFP8) C8[(size_t)m * N + n] = f2e4m3(v);
                else        Cb[(size_t)m * N + n] = __float2bfloat16(v);
            }
        }
    }
#undef STAGE8
}

// ============ FP8 GEMM (layer 3, 16x16) + fused tf partial-dot ============
__global__ __launch_bounds__(256, 2) void gemm128f8_pdot_kernel(
    const unsigned char* __restrict__ A,
    const unsigned char* __restrict__ Wt,
    const float* __restrict__ bias,
    const float* __restrict__ w4,
    float* __restrict__ pdot,   // [M][2]
    int K, int N) {
    __shared__ __align__(16) unsigned char Als[2][128 * 64];
    __shared__ __align__(16) unsigned char Bls[2][128 * 64];
    __shared__ float spd[128][2];
    const int tid = threadIdx.x;
    const int wave = tid >> 6, lane = tid & 63;
    const int m0 = blockIdx.x * 128, n0 = blockIdx.y * 128;
    const int nb = blockIdx.y;
    const int wr = wave >> 1, wc = wave & 1;
    const int fr = lane & 15, fq = lane >> 4;

    int sr[2], skel[2], sbase[2];
#pragma unroll
    for (int j = 0; j < 2; ++j) {
        int c = j * 256 + tid;
        int row = c >> 2;
        int inner = (c & 3) * 16;
        skel[j] = inner ^ ((row & 6) << 3);
        sr[j] = row;
        sbase[j] = (j * 256 + wave * 64) * 16;
    }
    int aoff[4], boff[4];
#pragma unroll
    for (int f = 0; f < 4; ++f) {
        int rA = wr * 64 + f * 16 + fr;
        aoff[f] = rA * 64 + ((fq * 8) ^ ((rA & 6) << 3));
        int rB = wc * 64 + f * 16 + fr;
        boff[f] = rB * 64 + ((fq * 8) ^ ((rB & 6) << 3));
    }

    f32x4 acc[4][4] = {};
    long av[4], bv[4];

#define STAGE8(bufn, kt) do {                                                         \
    _Pragma("unroll") for (int j = 0; j < 2; ++j) {                                   \
        GLD_LDS16(A + (size_t)(m0 + sr[j]) * K + (kt) + skel[j], (char*)Als[bufn] + sbase[j]); \
        GLD_LDS16(Wt + (size_t)(n0 + sr[j]) * K + (kt) + skel[j], (char*)Bls[bufn] + sbase[j]); \
    }                                                                                 \
} while (0)

    STAGE8(0, 0);
    __syncthreads();

    const int nt = K >> 6;
    for (int t = 0; t < nt; ++t) {
        const int buf = t & 1;
#pragma unroll
        for (int f = 0; f < 4; ++f) bv[f] = *(const long*)(&Bls[buf][boff[f]]);
#pragma unroll
        for (int f = 0; f < 4; ++f) av[f] = *(const long*)(&Als[buf][aoff[f]]);
        if (t + 1 < nt) STAGE8(buf ^ 1, (t + 1) << 6);
        __builtin_amdgcn_s_setprio(1);
#pragma unroll
        for (int mi = 0; mi < 4; ++mi)
#pragma unroll
            for (int ni = 0; ni < 4; ++ni)
                acc[mi][ni] = __builtin_amdgcn_mfma_f32_16x16x32_fp8_fp8(
                    av[mi], bv[ni], acc[mi][ni], 0, 0, 0);
        __builtin_amdgcn_s_setprio(0);
#pragma unroll
        for (int f = 0; f < 4; ++f) bv[f] = *(const long*)(&Bls[buf][boff[f] ^ 32]);
#pragma unroll
        for (int f = 0; f < 4; ++f) av[f] = *(const long*)(&Als[buf][aoff[f] ^ 32]);
        __builtin_amdgcn_s_setprio(1);
#pragma unroll
        for (int mi = 0; mi < 4; ++mi)
#pragma unroll
            for (int ni = 0; ni < 4; ++ni)
                acc[mi][ni] = __builtin_amdgcn_mfma_f32_16x16x32_fp8_fp8(
                    av[mi], bv[ni], acc[mi][ni], 0, 0, 0);
        __builtin_amdgcn_s_setprio(0);
        __syncthreads();
    }

    // per-row partial dot over this block's 128 columns (deterministic)
    float pd[4][4];
#pragma unroll
    for (int mi = 0; mi < 4; ++mi)
#pragma unroll
        for (int r = 0; r < 4; ++r) {
            float s = 0.f;
#pragma unroll
            for (int ni = 0; ni < 4; ++ni) {
                int n = n0 + wc * 64 + ni * 16 + fr;
                s += gelu_fast(fmaf(acc[mi][ni][r], INV_WSCALE, bias[n])) * w4[n];
            }
            pd[mi][r] = s;
        }
#pragma unroll
    for (int off = 1; off < 16; off <<= 1)
#pragma unroll
        for (int mi = 0; mi < 4; ++mi)
#pragma unroll
            for (int r = 0; r < 4; ++r)
                pd[mi][r] += __shfl_xor(pd[mi][r], off);
    if (fr == 0) {
#pragma unroll
        for (int mi = 0; mi < 4; ++mi)
#pragma unroll
            for (int r = 0; r < 4; ++r)
                spd[wr * 64 + mi * 16 + fq * 4 + r][wc] = pd[mi][r];
    }
    __syncthreads();
    if (tid < 128) pdot[(size_t)(m0 + tid) * 2 + nb] = spd[tid][0] + spd[tid][1];
#undef STAGE8
}

// ---------------- tf + coupling + twist update; bf16 state, fp8 operand copy ----------------
__global__ __launch_bounds__(256) void tf_update_kernel(
    const float* __restrict__ srcf, const __hip_bfloat16* __restrict__ srcb, int use_bf,
    const float* __restrict__ pdot,  // [ROWS][2]
    const float* __restrict__ b4,
    const float* __restrict__ gf, const float* __restrict__ arp,
    float* __restrict__ out, __hip_bfloat16* __restrict__ outb,
    unsigned char* __restrict__ outb8, int wf, int wb, int w8) {
    const int wid = threadIdx.x >> 6, lane = threadIdx.x & 63;
    const int r = blockIdx.x * 4 + wid;
    const int b = r >> 12;  // S = 4096 rows per batch

    float2 pv = reinterpret_cast<const float2*>(pdot)[r];
    float tf = sigmf_(pv.x + pv.y + b4[0]);
    float comb = 0.7f * gf[b] + 0.3f * tf;
    float c = BASE_COUPLING + arp[0] * (comb - 0.5f) * 2.0f;

    float4 o_r, o_i, p_r, p_i;
    if (use_bf) {
        const uint2* s2 = reinterpret_cast<const uint2*>(srcb + (size_t)r * PD);
        o_r = ubf2f4(s2[lane]);
        o_i = ubf2f4(s2[64 + lane]);
        p_r = ubf2f4(s2[128 + lane]);
        p_i = ubf2f4(s2[192 + lane]);
    } else {
        const float4* s4 = reinterpret_cast<const float4*>(srcf + (size_t)r * PD);
        o_r = s4[lane];
        o_i = s4[64 + lane];
        p_r = s4[128 + lane];
        p_i = s4[192 + lane];
    }
    float4 n0 = axpy4(o_r, c, p_r);
    float4 n1 = axpy4(o_i, -c, p_i);
    float4 n2 = axpy4(p_r, -c, o_r);
    float4 n3 = axpy4(p_i, c, o_i);
    if (wf) {
        float4* row4 = reinterpret_cast<float4*>(out + (size_t)r * PD);
        row4[lane] = n0;
        row4[64 + lane] = n1;
        row4[128 + lane] = n2;
        row4[192 + lane] = n3;
    }
    if (wb) {
        uint2* rb4 = reinterpret_cast<uint2*>(outb + (size_t)r * PD);
        rb4[lane] = pk4(n0);
        rb4[64 + lane] = pk4(n1);
        rb4[128 + lane] = pk4(n2);
        rb4[192 + lane] = pk4(n3);
    }
    if (w8) {
        unsigned int* r8 = reinterpret_cast<unsigned int*>(outb8 + (size_t)r * PD);
        r8[lane] = pk8(n0);
        r8[64 + lane] = pk8(n1);
        r8[128 + lane] = pk8(n2);
        r8[192 + lane] = pk8(n3);
    }
}

// ---------------- launch ----------------
extern "C" void kernel_launch(void* const* d_in, const int* in_sizes, int n_in,
                              void* d_out, int out_size, void* d_ws, size_t ws_size,
                              hipStream_t stream) {
    const float* x     = (const float*)d_in[0];
    const float* cn_w1 = (const float*)d_in[1];
    const float* cn_b1 = (const float*)d_in[2];
    const float* cn_w2 = (const float*)d_in[3];
    const float* cn_b2 = (const float*)d_in[4];
    const float* cn_w3 = (const float*)d_in[5];
    const float* cn_b3 = (const float*)d_in[6];
    const float* cn_w4 = (const float*)d_in[7];
    const float* cn_b4 = (const float*)d_in[8];
    const float* gc_w1 = (const float*)d_in[9];
    const float* gc_b1 = (const float*)d_in[10];
    const float* gc_w2 = (const float*)d_in[11];
    const float* gc_b2 = (const float*)d_in[12];
    const float* gc_w3 = (const float*)d_in[13];
    const float* gc_b3 = (const float*)d_in[14];
    const float* ar    = (const float*)d_in[15];

    float* out = (float*)d_out;

    // workspace layout (~80 MB)
    char* ws = (char*)d_ws;
    unsigned char* h1_8   = (unsigned char*)(ws);                                   // 16 MB
    unsigned char* h2_8   = (unsigned char*)(ws + ((size_t)16 << 20));              // 8 MB
    __hip_bfloat16* outb  = (__hip_bfloat16*)(ws + ((size_t)24 << 20));             // 32 MB (bf16 state)
    unsigned char* outb8  = (unsigned char*)(ws + ((size_t)56 << 20));              // 16 MB (fp8 operand)
    unsigned char* wt1_8  = (unsigned char*)(ws + ((size_t)72 << 20));              // 1 MB
    unsigned char* wt2_8  = (unsigned char*)(ws + ((size_t)73 << 20));              // 0.5 MB
    unsigned char* wt3_8  = (unsigned char*)(ws + ((size_t)73 << 20) + ((size_t)1 << 19)); // 128 KB
    float* pdot           = (float*)(ws + ((size_t)74 << 20));                      // 128 KB
    float* part           = (float*)(ws + ((size_t)75 << 20));                      // 2 MB
    float* gc             = (float*)(ws + ((size_t)77 << 20));                      // small
    float* g1             = gc + 4 * PD;
    float* g2             = g1 + 4 * 512;
    float* gf             = g2 + 4 * 256;

    // weights -> fp8 (scaled x256)
    transpose_w8_kernel<<<dim3(32, 32), 256, 0, stream>>>(cn_w1, wt1_8, 1024, 1024);
    transpose_w8_kernel<<<dim3(32, 16), 256, 0, stream>>>(cn_w2, wt2_8, 1024, 512);
    transpose_w8_kernel<<<dim3(16, 8), 256, 0, stream>>>(cn_w3, wt3_8, 512, 256);

    copy_mean_cvt_kernel<<<512, 256, 0, stream>>>(x, outb8, part);
    mean_stage2<<<PB, 256, 0, stream>>>(part, gc);

    gn1_kernel<<<dim3(PB, 8), 256, 0, stream>>>(gc, gc_w1, gc_b1, g1);
    gn2_kernel<<<dim3(PB, 4), 256, 0, stream>>>(g1, gc_w2, gc_b2, g2);
    gn3_kernel<<<PB, 256, 0, stream>>>(g2, gc_w3, gc_b3, gf);

    for (int cyc = 0; cyc < NUM_CYCLES; ++cyc) {
        // L1: fp8 16x16 MFMA, fp8 out
        gemm128f8_kernel<1><<<dim3(128, 8), 256, 0, stream>>>(
            outb8, wt1_8, cn_b1, h1_8, nullptr, 1024, 1024);
        // L2: fp8 16x16 MFMA, fp8 out
        gemm128f8_kernel<1><<<dim3(128, 4), 256, 0, stream>>>(
            h1_8, wt2_8, cn_b2, h2_8, nullptr, 1024, 512);
        // L3: fp8 16x16 MFMA, fused pdot
        gemm128f8_pdot_kernel<<<dim3(128, 2), 256, 0, stream>>>(
            h2_8, wt3_8, cn_b3, cn_w4, pdot, 512, 256);
        int last = (cyc + 1 == NUM_CYCLES);
        tf_update_kernel<<<ROWS / 4, 256, 0, stream>>>(
            x, outb, (cyc > 0) ? 1 : 0, pdot, cn_b4, gf, ar,
            out, outb, outb8, last ? 1 : 0, last ? 0 : 1, last ? 0 : 1);
    }
}